// Round 16
// baseline (268.297 us; speedup 1.0000x reference)
//
#include <hip/hip_runtime.h>
#include <hip/hip_bf16.h>
#include <stdint.h>

typedef __attribute__((ext_vector_type(8))) short bf16x8;
typedef __attribute__((ext_vector_type(4))) float f32x4;

#define LSEQ 2048
#define DM 1024
#define NH 16
#define HD 64

__device__ __forceinline__ unsigned short bf16r(float f) {
  unsigned u = __builtin_bit_cast(unsigned, f);
  u = (u + 0x7FFFu + ((u >> 16) & 1u)) >> 16;
  return (unsigned short)u;
}
__device__ __forceinline__ float bf16f(unsigned short h) {
  unsigned u = ((unsigned)h) << 16;
  return __builtin_bit_cast(float, u);
}
__device__ __forceinline__ unsigned cvt_pk_bf16(float a, float b) {
  unsigned r;
  asm("v_cvt_pk_bf16_f32 %0, %1, %2" : "=v"(r) : "v"(a), "v"(b));
  return r;
}

__device__ __forceinline__ void async16(const void* g, void* l) {
  __builtin_amdgcn_global_load_lds(
      (const __attribute__((address_space(1))) unsigned int*)g,
      (__attribute__((address_space(3))) unsigned int*)l, 16, 0, 0);
}

// swizzled ds_read_b128 from a 128B-row LDS tile (byte ^= (row&7)<<4)
__device__ __forceinline__ bf16x8 lds_frag_swz(const unsigned short* base, int row, int colbyte) {
  int addr = row * 128 + colbyte;
  addr ^= ((row & 7) << 4);
  return *(const bf16x8*)((const char*)base + addr);
}
// swizzled ds_read_b128 from a 256B-row LDS tile (byte ^= (row&15)<<4)
__device__ __forceinline__ bf16x8 lds_frag_swzV(const unsigned short* base, int row, int colbyte) {
  int addr = row * 256 + colbyte;
  addr ^= ((row & 15) << 4);
  return *(const bf16x8*)((const char*)base + addr);
}

// ---------------- f32 -> bf16 convert: 4 weight tensors ----------------
__global__ __launch_bounds__(256) void cvt4(const float* __restrict__ s0,
                                            const float* __restrict__ s1,
                                            const float* __restrict__ s2,
                                            const float* __restrict__ s3,
                                            unsigned short* __restrict__ d0,
                                            unsigned short* __restrict__ d1,
                                            unsigned short* __restrict__ d2,
                                            unsigned short* __restrict__ d3, int n8) {
  int y = blockIdx.y;
  const float* s = (y == 0) ? s0 : (y == 1) ? s1 : (y == 2) ? s2 : s3;
  unsigned short* d = (y == 0) ? d0 : (y == 1) ? d1 : (y == 2) ? d2 : d3;
  int i = blockIdx.x * 256 + threadIdx.x;
  if (i >= n8) return;
  const float4* sp = (const float4*)s;
  float4 a = sp[2 * i], b = sp[2 * i + 1];
  union { unsigned short u[8]; uint4 v; } r;
  r.u[0] = bf16r(a.x); r.u[1] = bf16r(a.y); r.u[2] = bf16r(a.z); r.u[3] = bf16r(a.w);
  r.u[4] = bf16r(b.x); r.u[5] = bf16r(b.y); r.u[6] = bf16r(b.z); r.u[7] = bf16r(b.w);
  ((uint4*)d)[i] = r.v;
}

// ---------------- GEMM core, 128x64 tile ----------------
// AF32: A is f32 in global; staged via reg (load f32x8 -> cvt_pk -> ds_write_b128).
// MODE 1: bf16 out + per-64-col L2 norm; 2: f32 out; 3: bf16 out transposed to Vt[B,H,64,L]
template <int MODE, bool AF32>
__device__ __forceinline__ void gemm_core64(const void* __restrict__ Ap,
                                            const unsigned short* __restrict__ Bw,
                                            const float* __restrict__ bias,
                                            void* __restrict__ Cout,
                                            unsigned short* As, unsigned short* Bs) {
  const int t = threadIdx.x, lane = t & 63, wid = t >> 6;
  const int mt = blockIdx.x, nt = blockIdx.y;
  const int wm = wid * 32;
  const int lq = lane >> 4, lr = lane & 15;

  f32x4 acc[2][4];
#pragma unroll
  for (int i = 0; i < 2; ++i)
#pragma unroll
    for (int j = 0; j < 4; ++j) acc[i][j] = (f32x4){0.f, 0.f, 0.f, 0.f};

  auto stage = [&](int k0) {
    if (AF32) {
      const float* Af = (const float*)Ap;
#pragma unroll
      for (int i = 0; i < 4; ++i) {  // A: 128 rows x 64 cols bf16 = 16KB in LDS
        int chunk = i * 256 + t;
        int row = chunk >> 3, j = chunk & 7;
        int sj = j ^ (row & 7);
        const float* src = Af + (size_t)(mt * 128 + row) * DM + k0 + sj * 8;
        float4 x0 = *(const float4*)src;
        float4 x1 = *(const float4*)(src + 4);
        union { unsigned w[4]; uint4 v; } o;
        o.w[0] = cvt_pk_bf16(x0.x, x0.y);
        o.w[1] = cvt_pk_bf16(x0.z, x0.w);
        o.w[2] = cvt_pk_bf16(x1.x, x1.y);
        o.w[3] = cvt_pk_bf16(x1.z, x1.w);
        *(uint4*)((char*)As + chunk * 16) = o.v;
      }
    } else {
      const unsigned short* A = (const unsigned short*)Ap;
#pragma unroll
      for (int i = 0; i < 4; ++i) {
        int chunk = i * 256 + t;
        int row = chunk >> 3, j = chunk & 7;
        int sj = j ^ (row & 7);
        async16(A + (size_t)(mt * 128 + row) * DM + k0 + sj * 8, (char*)As + chunk * 16);
      }
    }
#pragma unroll
    for (int i = 0; i < 2; ++i) {  // B: 64 rows x 64 cols = 8KB
      int chunk = i * 256 + t;
      int row = chunk >> 3, j = chunk & 7;
      int sj = j ^ (row & 7);
      async16(Bw + (size_t)(nt * 64 + row) * DM + k0 + sj * 8, (char*)Bs + chunk * 16);
    }
  };

  stage(0);
  for (int kt = 0; kt < DM / 64; ++kt) {
    __syncthreads();
    bf16x8 af[2][2], bfr[4][2];
#pragma unroll
    for (int mf = 0; mf < 2; ++mf) {
      int row = wm + mf * 16 + lr;
#pragma unroll
      for (int ks = 0; ks < 2; ++ks)
        af[mf][ks] = lds_frag_swz(As, row, ks * 64 + lq * 16);
    }
#pragma unroll
    for (int nf = 0; nf < 4; ++nf) {
      int row = nf * 16 + lr;
#pragma unroll
      for (int ks = 0; ks < 2; ++ks)
        bfr[nf][ks] = lds_frag_swz(Bs, row, ks * 64 + lq * 16);
    }
    __syncthreads();
    if (kt + 1 < DM / 64) stage((kt + 1) * 64);
#pragma unroll
    for (int ks = 0; ks < 2; ++ks)
#pragma unroll
      for (int mf = 0; mf < 2; ++mf)
#pragma unroll
        for (int nf = 0; nf < 4; ++nf)
          acc[mf][nf] = __builtin_amdgcn_mfma_f32_16x16x32_bf16(af[mf][ks], bfr[nf][ks],
                                                                acc[mf][nf], 0, 0, 0);
  }

  const int gn0 = nt * 64;
  float bv[4];
#pragma unroll
  for (int nf = 0; nf < 4; ++nf) bv[nf] = bias[gn0 + nf * 16 + lr];
#pragma unroll
  for (int mf = 0; mf < 2; ++mf) {
    float v[4][4];
#pragma unroll
    for (int nf = 0; nf < 4; ++nf)
#pragma unroll
      for (int r = 0; r < 4; ++r) v[nf][r] = acc[mf][nf][r] + bv[nf];
    if (MODE == 1) {
#pragma unroll
      for (int r = 0; r < 4; ++r) {
        float ss = v[0][r] * v[0][r] + v[1][r] * v[1][r] + v[2][r] * v[2][r] + v[3][r] * v[3][r];
        ss += __shfl_xor(ss, 1, 64);
        ss += __shfl_xor(ss, 2, 64);
        ss += __shfl_xor(ss, 4, 64);
        ss += __shfl_xor(ss, 8, 64);
        float rn = 1.0f / fmaxf(sqrtf(ss), 1e-12f);
#pragma unroll
        for (int nf = 0; nf < 4; ++nf) v[nf][r] *= rn;
      }
    }
    const int gm0 = mt * 128 + wm + mf * 16 + lq * 4;
    if (MODE == 2) {
      float* C = (float*)Cout;
#pragma unroll
      for (int r = 0; r < 4; ++r)
#pragma unroll
        for (int nf = 0; nf < 4; ++nf)
          C[(size_t)(gm0 + r) * DM + gn0 + nf * 16 + lr] = v[nf][r];
    } else if (MODE == 3) {
      unsigned short* Vt = (unsigned short*)Cout;
      const int bb = gm0 >> 11, ll = gm0 & 2047;
#pragma unroll
      for (int nf = 0; nf < 4; ++nf) {
        int col = gn0 + nf * 16 + lr;
        int hh = col >> 6, dd = col & 63;
        ushort4 o;
        o.x = bf16r(v[nf][0]); o.y = bf16r(v[nf][1]);
        o.z = bf16r(v[nf][2]); o.w = bf16r(v[nf][3]);
        *(ushort4*)&Vt[(size_t)((bb * NH + hh) * HD + dd) * LSEQ + ll] = o;
      }
    } else {
      unsigned short* C = (unsigned short*)Cout;
#pragma unroll
      for (int r = 0; r < 4; ++r)
#pragma unroll
        for (int nf = 0; nf < 4; ++nf)
          C[(size_t)(gm0 + r) * DM + gn0 + nf * 16 + lr] = bf16r(v[nf][r]);
    }
  }
}

__global__ __launch_bounds__(256) void gemm_qkv(
    const float* __restrict__ A0, const float* __restrict__ A1, const float* __restrict__ A2,
    const unsigned short* __restrict__ W0, const unsigned short* __restrict__ W1,
    const unsigned short* __restrict__ W2, const float* __restrict__ b0,
    const float* __restrict__ b1, const float* __restrict__ b2,
    unsigned short* __restrict__ C0, unsigned short* __restrict__ C1,
    unsigned short* __restrict__ C2) {
  __shared__ unsigned short As[128 * 64];
  __shared__ unsigned short Bs[64 * 64];
  int z = blockIdx.z;
  if (z == 0) gemm_core64<1, true>(A0, W0, b0, C0, As, Bs);
  else if (z == 1) gemm_core64<1, true>(A1, W1, b1, C1, As, Bs);
  else gemm_core64<3, true>(A2, W2, b2, C2, As, Bs);
}

__global__ __launch_bounds__(256) void gemm_o(const unsigned short* __restrict__ A,
                                              const unsigned short* __restrict__ W,
                                              const float* __restrict__ bias,
                                              float* __restrict__ C) {
  __shared__ unsigned short As[128 * 64];
  __shared__ unsigned short Bs[64 * 64];
  gemm_core64<2, false>(A, W, bias, C, As, Bs);
}

// ---------------- fused cosine attention, 2x2 wave split + counted-vmcnt pass 2 ----------------
// R7 structure verbatim (validated 5x).
__global__ __launch_bounds__(256, 4) void attn_kernel(
    const unsigned short* __restrict__ Qn, const unsigned short* __restrict__ Kn,
    const unsigned short* __restrict__ Vt, const int* __restrict__ mask,
    const float* __restrict__ scale_p, float* __restrict__ attn_out,
    unsigned short* __restrict__ ctx) {
  __shared__ unsigned short QVs[64 * 128];  // Q [64q][128B] (8KB) then V [64d][256B] (16KB)
  __shared__ unsigned short Ks[128 * 64];   // [128k][128B] 16KB; f32 ctx scratch at end
  __shared__ unsigned short Ms[2048];       // mask as bf16 {0,1}, 4KB
  __shared__ float Rs[2][2][32];            // rowsum partials [qg][kg][q]

  // XCD-chunked swizzle: 1024 blocks, 128 per XCD -> 4 (b,h) K/V panels per XCD L2
  const int raw = blockIdx.x;
  const int swz = (raw & 7) * 128 + (raw >> 3);
  const int qt = swz & 31, h = (swz >> 5) & 15, b = swz >> 9;

  const int t = threadIdx.x, lane = t & 63, wid = t >> 6;
  const int lq = lane >> 4, lr = lane & 15;
  const int qg = wid >> 1, kg = wid & 1;
  const float k2 = scale_p[0] * 1.4426950408889634f;

  const unsigned short* Qg = Qn + ((size_t)(b * LSEQ + qt * 64) * DM + h * HD);
  const unsigned short* Kg = Kn + ((size_t)b * LSEQ * DM + h * HD);
  const unsigned short* Vg = Vt + (size_t)(b * NH + h) * HD * LSEQ;
  float* attn_g = attn_out + ((size_t)((b * NH + h) * LSEQ + qt * 64)) * LSEQ;
  const int* mg = mask + b * LSEQ;

  auto stageK = [&](int k0) {
#pragma unroll
    for (int i = 0; i < 4; ++i) {
      int chunk = i * 256 + t;
      int row = chunk >> 3, j = chunk & 7;
      async16(Kg + (size_t)(k0 + row) * DM + (j ^ (row & 7)) * 8, (char*)Ks + chunk * 16);
    }
  };
  auto stageV = [&](int k0) {
#pragma unroll
    for (int i = 0; i < 4; ++i) {
      int chunk = i * 256 + t;
      int row = chunk >> 4, j = chunk & 15;
      async16(Vg + (size_t)row * LSEQ + k0 + (j ^ (row & 15)) * 8, (char*)QVs + chunk * 16);
    }
  };

  // mask -> Ms (bf16 0/1)
  {
    const int4* mp = (const int4*)mg;
    int4 m0 = mp[t * 2], m1 = mp[t * 2 + 1];
    union { unsigned short u[8]; uint4 v; } mo;
    mo.u[0] = m0.x ? 0x3F80 : 0; mo.u[1] = m0.y ? 0x3F80 : 0;
    mo.u[2] = m0.z ? 0x3F80 : 0; mo.u[3] = m0.w ? 0x3F80 : 0;
    mo.u[4] = m1.x ? 0x3F80 : 0; mo.u[5] = m1.y ? 0x3F80 : 0;
    mo.u[6] = m1.z ? 0x3F80 : 0; mo.u[7] = m1.w ? 0x3F80 : 0;
    ((uint4*)Ms)[t] = mo.v;
  }
  // stage Q + K tile 0
#pragma unroll
  for (int i = 0; i < 2; ++i) {
    int chunk = i * 256 + t;
    int row = chunk >> 3, j = chunk & 7;
    async16(Qg + (size_t)row * DM + (j ^ (row & 7)) * 8, (char*)QVs + chunk * 16);
  }
  stageK(0);

  bf16x8 qb[2][2];  // [qf][dh]
  float rs[2] = {0.f, 0.f};

  // ---- pass 1: denominators ----
  for (int kt = 0; kt < LSEQ / 128; ++kt) {
    __syncthreads();
    if (kt == 0) {
#pragma unroll
      for (int qf = 0; qf < 2; ++qf)
#pragma unroll
        for (int dh = 0; dh < 2; ++dh)
          qb[qf][dh] = lds_frag_swz(QVs, qg * 32 + qf * 16 + lr, dh * 64 + lq * 16);
    }
#pragma unroll
    for (int kf = 0; kf < 4; ++kf) {
      int krow = kg * 64 + kf * 16 + lr;
      bf16x8 a0 = lds_frag_swz(Ks, krow, lq * 16);
      bf16x8 a1 = lds_frag_swz(Ks, krow, 64 + lq * 16);
      ushort4 m4 = *(const ushort4*)&Ms[kt * 128 + kg * 64 + kf * 16 + lq * 4];
#pragma unroll
      for (int qf = 0; qf < 2; ++qf) {
        f32x4 z = (f32x4){0.f, 0.f, 0.f, 0.f};
        z = __builtin_amdgcn_mfma_f32_16x16x32_bf16(a0, qb[qf][0], z, 0, 0, 0);
        z = __builtin_amdgcn_mfma_f32_16x16x32_bf16(a1, qb[qf][1], z, 0, 0, 0);
        rs[qf] += __builtin_amdgcn_exp2f(z[0] * k2) * bf16f(m4.x);
        rs[qf] += __builtin_amdgcn_exp2f(z[1] * k2) * bf16f(m4.y);
        rs[qf] += __builtin_amdgcn_exp2f(z[2] * k2) * bf16f(m4.z);
        rs[qf] += __builtin_amdgcn_exp2f(z[3] * k2) * bf16f(m4.w);
      }
    }
    __syncthreads();
    if (kt + 1 < LSEQ / 128) stageK((kt + 1) * 128);
  }
  // reduce rs over lq within wave, publish per (qg,kg); fold staging of tile 0
  // into the same barrier (all waves passed last B2, so Ks/QVs reads are done).
#pragma unroll
  for (int qf = 0; qf < 2; ++qf) {
    rs[qf] += __shfl_xor(rs[qf], 16, 64);
    rs[qf] += __shfl_xor(rs[qf], 32, 64);
  }
  stageK(0);
  stageV(0);
  if (lq == 0) {
    Rs[qg][kg][lr] = rs[0];
    Rs[qg][kg][16 + lr] = rs[1];
  }
  __syncthreads();  // drains vmcnt(0): tile-0 staging complete + Rs visible
  float sinv[2];
#pragma unroll
  for (int qf = 0; qf < 2; ++qf) {
    float tot = Rs[qg][0][qf * 16 + lr] + Rs[qg][1][qf * 16 + lr];
    sinv[qf] = 1.0f / fmaxf(tot, 1e-30f);
  }

  // ---- pass 2: recompute, accumulate PV, deferred NT attn stores ----
  f32x4 acc[4][2];  // [df][qf]
#pragma unroll
  for (int df = 0; df < 4; ++df)
#pragma unroll
    for (int qf = 0; qf < 2; ++qf) acc[df][qf] = (f32x4){0.f, 0.f, 0.f, 0.f};
  const int sA = ((lane & 16) ? 32 : 0) + lr;  // bpermute source lanes
  const int sB = sA + 16;
  const bool selHi = (lane & 32) != 0;

#pragma unroll 1
  for (int kt = 0; kt < LSEQ / 128; ++kt) {
    unsigned pk[4][2][2];
#pragma unroll
    for (int kf = 0; kf < 4; ++kf) {
      int krow = kg * 64 + kf * 16 + lr;
      bf16x8 a0 = lds_frag_swz(Ks, krow, lq * 16);
      bf16x8 a1 = lds_frag_swz(Ks, krow, 64 + lq * 16);
      ushort4 m4 = *(const ushort4*)&Ms[kt * 128 + kg * 64 + kf * 16 + lq * 4];
#pragma unroll
      for (int qf = 0; qf < 2; ++qf) {
        f32x4 z = (f32x4){0.f, 0.f, 0.f, 0.f};
        z = __builtin_amdgcn_mfma_f32_16x16x32_bf16(a0, qb[qf][0], z, 0, 0, 0);
        z = __builtin_amdgcn_mfma_f32_16x16x32_bf16(a1, qb[qf][1], z, 0, 0, 0);
        float p0 = __builtin_amdgcn_exp2f(z[0] * k2) * bf16f(m4.x) * sinv[qf];
        float p1 = __builtin_amdgcn_exp2f(z[1] * k2) * bf16f(m4.y) * sinv[qf];
        float p2 = __builtin_amdgcn_exp2f(z[2] * k2) * bf16f(m4.z) * sinv[qf];
        float p3 = __builtin_amdgcn_exp2f(z[3] * k2) * bf16f(m4.w) * sinv[qf];
        pk[kf][qf][0] = cvt_pk_bf16(p0, p1);
        pk[kf][qf][1] = cvt_pk_bf16(p2, p3);
      }
    }
    // PV: pb word j for lane lq covers keys kh*32+lq*8+2j{,+1}
#pragma unroll
    for (int kh = 0; kh < 2; ++kh) {
      bf16x8 pbv[2];
#pragma unroll
      for (int qf = 0; qf < 2; ++qf) {
        union { unsigned w[4]; bf16x8 v; } pb;
        unsigned lo0 = __shfl((int)pk[kh * 2][qf][0], sA, 64);
        unsigned hi0 = __shfl((int)pk[kh * 2 + 1][qf][0], sA, 64);
        unsigned lo1 = __shfl((int)pk[kh * 2][qf][1], sA, 64);
        unsigned hi1 = __shfl((int)pk[kh * 2 + 1][qf][1], sA, 64);
        unsigned lo2 = __shfl((int)pk[kh * 2][qf][0], sB, 64);
        unsigned hi2 = __shfl((int)pk[kh * 2 + 1][qf][0], sB, 64);
        unsigned lo3 = __shfl((int)pk[kh * 2][qf][1], sB, 64);
        unsigned hi3 = __shfl((int)pk[kh * 2 + 1][qf][1], sB, 64);
        pb.w[0] = selHi ? hi0 : lo0;
        pb.w[1] = selHi ? hi1 : lo1;
        pb.w[2] = selHi ? hi2 : lo2;
        pb.w[3] = selHi ? hi3 : lo3;
        pbv[qf] = pb.v;
      }
#pragma unroll
      for (int df = 0; df < 4; ++df) {
        bf16x8 va = lds_frag_swzV(QVs, df * 16 + lr, kg * 128 + kh * 64 + lq * 16);
#pragma unroll
        for (int qf = 0; qf < 2; ++qf)
          acc[df][qf] = __builtin_amdgcn_mfma_f32_16x16x32_bf16(va, pbv[qf], acc[df][qf], 0, 0, 0);
      }
    }
    // B2: all LDS reads of this tile done (lgkm only — do NOT drain NT stores)
    asm volatile("s_waitcnt lgkmcnt(0)" ::: "memory");
    __builtin_amdgcn_s_barrier();
    // stage next tile FIRST (8 older vmem loads)...
    if (kt + 1 < LSEQ / 128) { stageK((kt + 1) * 128); stageV((kt + 1) * 128); }
    __builtin_amdgcn_sched_barrier(0);
    // ...then this tile's 8 NT attn stores (youngest 8 vmem ops)
#pragma unroll
    for (int kf = 0; kf < 4; ++kf)
#pragma unroll
      for (int qf = 0; qf < 2; ++qf) {
        unsigned w0 = pk[kf][qf][0], w1 = pk[kf][qf][1];
        f32x4 st;
        st[0] = __builtin_bit_cast(float, w0 << 16);
        st[1] = __builtin_bit_cast(float, w0 & 0xFFFF0000u);
        st[2] = __builtin_bit_cast(float, w1 << 16);
        st[3] = __builtin_bit_cast(float, w1 & 0xFFFF0000u);
        __builtin_nontemporal_store(
            st, (f32x4*)(attn_g + (size_t)(qg * 32 + qf * 16 + lr) * LSEQ + kt * 128 +
                         kg * 64 + kf * 16 + lq * 4));
      }
    if (kt + 1 < LSEQ / 128) {
      // B1: staging retired (8 youngest = our stores may remain in flight)
      asm volatile("s_waitcnt vmcnt(8)" ::: "memory");
      __builtin_amdgcn_s_barrier();
    }
  }

  // ---- cross-wave k-reduction via LDS scratch (overlaid on Ks) ----
  __syncthreads();  // drains last tile's stores once (kernel epilogue)
  float* CR = (float*)Ks;  // [2 qg][32 q][64 d] f32, 16KB, swizzled
  if (kg == 1) {
#pragma unroll
    for (int df = 0; df < 4; ++df)
#pragma unroll
      for (int qf = 0; qf < 2; ++qf) {
        int q = qf * 16 + lr, dd = df * 16 + lq * 4;
        int byte = ((qg * 32 + q) * 64 + dd) * 4;
        byte ^= (q & 7) << 4;
        *(f32x4*)((char*)CR + byte) = acc[df][qf];
      }
  }
  __syncthreads();
  if (kg == 0) {
#pragma unroll
    for (int df = 0; df < 4; ++df)
#pragma unroll
      for (int qf = 0; qf < 2; ++qf) {
        int q = qf * 16 + lr, dd = df * 16 + lq * 4;
        int byte = ((qg * 32 + q) * 64 + dd) * 4;
        byte ^= (q & 7) << 4;
        f32x4 o = *(const f32x4*)((const char*)CR + byte);
        o += acc[df][qf];
        ushort4 st;
        st.x = bf16r(o[0]); st.y = bf16r(o[1]); st.z = bf16r(o[2]); st.w = bf16r(o[3]);
        *(ushort4*)&ctx[(size_t)(b * LSEQ + qt * 64 + qg * 32 + q) * DM + h * HD + dd] = st;
      }
  }
}

extern "C" void kernel_launch(void* const* d_in, const int* in_sizes, int n_in,
                              void* d_out, int out_size, void* d_ws, size_t ws_size,
                              hipStream_t stream) {
  const float* query = (const float*)d_in[0];
  const float* key_ = (const float*)d_in[1];
  const float* value = (const float*)d_in[2];
  const int* mask = (const int*)d_in[3];
  const float* Wq = (const float*)d_in[4];
  const float* bq = (const float*)d_in[5];
  const float* Wk = (const float*)d_in[6];
  const float* bk = (const float*)d_in[7];
  const float* Wv = (const float*)d_in[8];
  const float* bv = (const float*)d_in[9];
  const float* Wo = (const float*)d_in[10];
  const float* bo = (const float*)d_in[11];
  const float* scale = (const float*)d_in[12];

  char* ws = (char*)d_ws;
  const size_t XB = 8388608;   // 4Mi bf16
  const size_t WB = 2097152;   // 1Mi bf16
  unsigned short* wqb = (unsigned short*)(ws + 3 * XB);
  unsigned short* wkb = (unsigned short*)(ws + 3 * XB + WB);
  unsigned short* wvb = (unsigned short*)(ws + 3 * XB + 2 * WB);
  unsigned short* wob = (unsigned short*)(ws + 3 * XB + 3 * WB);
  unsigned short* Qnb = (unsigned short*)(ws + 3 * XB + 4 * WB);
  unsigned short* Knb = (unsigned short*)(ws + 4 * XB + 4 * WB);
  unsigned short* Vtb = (unsigned short*)(ws + 5 * XB + 4 * WB);
  unsigned short* ctxb = (unsigned short*)(ws + 6 * XB + 4 * WB);

  cvt4<<<dim3(512, 4), 256, 0, stream>>>(Wq, Wk, Wv, Wo, wqb, wkb, wvb, wob, 131072);

  gemm_qkv<<<dim3(32, 16, 3), 256, 0, stream>>>(query, key_, value, wqb, wkb, wvb,
                                                bq, bk, bv, Qnb, Knb, Vtb);

  float* attn_out = (float*)d_out + 4194304;
  attn_kernel<<<1024, 256, 0, stream>>>(Qnb, Knb, Vtb, mask, scale, attn_out, ctxb);

  gemm_o<<<dim3(32, 16), 256, 0, stream>>>(ctxb, wob, bo, (float*)d_out);
}

// Round 17
// 254.537 us; speedup vs baseline: 1.0541x; 1.0541x over previous
//
#include <hip/hip_runtime.h>
#include <hip/hip_bf16.h>
#include <stdint.h>

typedef __attribute__((ext_vector_type(8))) short bf16x8;
typedef __attribute__((ext_vector_type(4))) float f32x4;

#define LSEQ 2048
#define DM 1024
#define NH 16
#define HD 64

__device__ __forceinline__ unsigned short bf16r(float f) {
  unsigned u = __builtin_bit_cast(unsigned, f);
  u = (u + 0x7FFFu + ((u >> 16) & 1u)) >> 16;
  return (unsigned short)u;
}
__device__ __forceinline__ float bf16f(unsigned short h) {
  unsigned u = ((unsigned)h) << 16;
  return __builtin_bit_cast(float, u);
}
__device__ __forceinline__ unsigned cvt_pk_bf16(float a, float b) {
  unsigned r;
  asm("v_cvt_pk_bf16_f32 %0, %1, %2" : "=v"(r) : "v"(a), "v"(b));
  return r;
}

__device__ __forceinline__ void async16(const void* g, void* l) {
  __builtin_amdgcn_global_load_lds(
      (const __attribute__((address_space(1))) unsigned int*)g,
      (__attribute__((address_space(3))) unsigned int*)l, 16, 0, 0);
}

// swizzled ds_read_b128 from a 128B-row LDS tile (byte ^= (row&7)<<4)
__device__ __forceinline__ bf16x8 lds_frag_swz(const unsigned short* base, int row, int colbyte) {
  int addr = row * 128 + colbyte;
  addr ^= ((row & 7) << 4);
  return *(const bf16x8*)((const char*)base + addr);
}
// swizzled ds_read_b128 from a 256B-row LDS tile (byte ^= (row&15)<<4)
__device__ __forceinline__ bf16x8 lds_frag_swzV(const unsigned short* base, int row, int colbyte) {
  int addr = row * 256 + colbyte;
  addr ^= ((row & 15) << 4);
  return *(const bf16x8*)((const char*)base + addr);
}

// ---------------- f32 -> bf16 convert: all 7 tensors in one launch ----------------
__global__ __launch_bounds__(256) void cvt7(
    const float* __restrict__ s0, const float* __restrict__ s1, const float* __restrict__ s2,
    const float* __restrict__ s3, const float* __restrict__ s4, const float* __restrict__ s5,
    const float* __restrict__ s6, unsigned short* __restrict__ d0,
    unsigned short* __restrict__ d1, unsigned short* __restrict__ d2,
    unsigned short* __restrict__ d3, unsigned short* __restrict__ d4,
    unsigned short* __restrict__ d5, unsigned short* __restrict__ d6) {
  int y = blockIdx.y;
  const float* s = (y == 0) ? s0 : (y == 1) ? s1 : (y == 2) ? s2
                  : (y == 3) ? s3 : (y == 4) ? s4 : (y == 5) ? s5 : s6;
  unsigned short* d = (y == 0) ? d0 : (y == 1) ? d1 : (y == 2) ? d2
                     : (y == 3) ? d3 : (y == 4) ? d4 : (y == 5) ? d5 : d6;
  int n8 = (y < 3) ? 524288 : 131072;
  int i = blockIdx.x * 256 + threadIdx.x;
  if (i >= n8) return;
  const float4* sp = (const float4*)s;
  float4 a = sp[2 * i], b = sp[2 * i + 1];
  union { unsigned short u[8]; uint4 v; } r;
  r.u[0] = bf16r(a.x); r.u[1] = bf16r(a.y); r.u[2] = bf16r(a.z); r.u[3] = bf16r(a.w);
  r.u[4] = bf16r(b.x); r.u[5] = bf16r(b.y); r.u[6] = bf16r(b.z); r.u[7] = bf16r(b.w);
  ((uint4*)d)[i] = r.v;
}

// ---------------- GEMM core, 128x64 tile: C[4096,1024] = A @ W^T + bias ----------------
// 4 waves, wave wid owns rows [wid*32, wid*32+32) x all 64 cols.
// MODE 1: bf16 out + per-64-col L2 norm; 2: f32 out; 3: bf16 out transposed to Vt[B,H,64,L]
template <int MODE>
__device__ __forceinline__ void gemm_core64(const unsigned short* __restrict__ A,
                                            const unsigned short* __restrict__ Bw,
                                            const float* __restrict__ bias,
                                            void* __restrict__ Cout,
                                            unsigned short* As, unsigned short* Bs) {
  const int t = threadIdx.x, lane = t & 63, wid = t >> 6;
  const int mt = blockIdx.x, nt = blockIdx.y;
  const int wm = wid * 32;
  const int lq = lane >> 4, lr = lane & 15;

  f32x4 acc[2][4];
#pragma unroll
  for (int i = 0; i < 2; ++i)
#pragma unroll
    for (int j = 0; j < 4; ++j) acc[i][j] = (f32x4){0.f, 0.f, 0.f, 0.f};

  auto stage = [&](int k0) {
#pragma unroll
    for (int i = 0; i < 4; ++i) {  // A: 128 rows x 64 cols = 16KB
      int chunk = i * 256 + t;
      int row = chunk >> 3, j = chunk & 7;
      int sj = j ^ (row & 7);
      async16(A + (size_t)(mt * 128 + row) * DM + k0 + sj * 8, (char*)As + chunk * 16);
    }
#pragma unroll
    for (int i = 0; i < 2; ++i) {  // B: 64 rows x 64 cols = 8KB
      int chunk = i * 256 + t;
      int row = chunk >> 3, j = chunk & 7;
      int sj = j ^ (row & 7);
      async16(Bw + (size_t)(nt * 64 + row) * DM + k0 + sj * 8, (char*)Bs + chunk * 16);
    }
  };

  stage(0);
  for (int kt = 0; kt < DM / 64; ++kt) {
    __syncthreads();
    bf16x8 af[2][2], bfr[4][2];
#pragma unroll
    for (int mf = 0; mf < 2; ++mf) {
      int row = wm + mf * 16 + lr;
#pragma unroll
      for (int ks = 0; ks < 2; ++ks)
        af[mf][ks] = lds_frag_swz(As, row, ks * 64 + lq * 16);
    }
#pragma unroll
    for (int nf = 0; nf < 4; ++nf) {
      int row = nf * 16 + lr;
#pragma unroll
      for (int ks = 0; ks < 2; ++ks)
        bfr[nf][ks] = lds_frag_swz(Bs, row, ks * 64 + lq * 16);
    }
    __syncthreads();
    if (kt + 1 < DM / 64) stage((kt + 1) * 64);
#pragma unroll
    for (int ks = 0; ks < 2; ++ks)
#pragma unroll
      for (int mf = 0; mf < 2; ++mf)
#pragma unroll
        for (int nf = 0; nf < 4; ++nf)
          acc[mf][nf] = __builtin_amdgcn_mfma_f32_16x16x32_bf16(af[mf][ks], bfr[nf][ks],
                                                                acc[mf][nf], 0, 0, 0);
  }

  const int gn0 = nt * 64;
  float bv[4];
#pragma unroll
  for (int nf = 0; nf < 4; ++nf) bv[nf] = bias[gn0 + nf * 16 + lr];
#pragma unroll
  for (int mf = 0; mf < 2; ++mf) {
    float v[4][4];
#pragma unroll
    for (int nf = 0; nf < 4; ++nf)
#pragma unroll
      for (int r = 0; r < 4; ++r) v[nf][r] = acc[mf][nf][r] + bv[nf];
    if (MODE == 1) {
#pragma unroll
      for (int r = 0; r < 4; ++r) {
        float ss = v[0][r] * v[0][r] + v[1][r] * v[1][r] + v[2][r] * v[2][r] + v[3][r] * v[3][r];
        ss += __shfl_xor(ss, 1, 64);
        ss += __shfl_xor(ss, 2, 64);
        ss += __shfl_xor(ss, 4, 64);
        ss += __shfl_xor(ss, 8, 64);
        float rn = 1.0f / fmaxf(sqrtf(ss), 1e-12f);
#pragma unroll
        for (int nf = 0; nf < 4; ++nf) v[nf][r] *= rn;
      }
    }
    const int gm0 = mt * 128 + wm + mf * 16 + lq * 4;
    if (MODE == 2) {
      float* C = (float*)Cout;
#pragma unroll
      for (int r = 0; r < 4; ++r)
#pragma unroll
        for (int nf = 0; nf < 4; ++nf)
          C[(size_t)(gm0 + r) * DM + gn0 + nf * 16 + lr] = v[nf][r];
    } else if (MODE == 3) {
      unsigned short* Vt = (unsigned short*)Cout;
      const int bb = gm0 >> 11, ll = gm0 & 2047;
#pragma unroll
      for (int nf = 0; nf < 4; ++nf) {
        int col = gn0 + nf * 16 + lr;
        int hh = col >> 6, dd = col & 63;
        ushort4 o;
        o.x = bf16r(v[nf][0]); o.y = bf16r(v[nf][1]);
        o.z = bf16r(v[nf][2]); o.w = bf16r(v[nf][3]);
        *(ushort4*)&Vt[(size_t)((bb * NH + hh) * HD + dd) * LSEQ + ll] = o;
      }
    } else {
      unsigned short* C = (unsigned short*)Cout;
#pragma unroll
      for (int r = 0; r < 4; ++r)
#pragma unroll
        for (int nf = 0; nf < 4; ++nf)
          C[(size_t)(gm0 + r) * DM + gn0 + nf * 16 + lr] = bf16r(v[nf][r]);
    }
  }
}

__global__ __launch_bounds__(256) void gemm_qkv(
    const unsigned short* __restrict__ A0, const unsigned short* __restrict__ A1,
    const unsigned short* __restrict__ A2, const unsigned short* __restrict__ W0,
    const unsigned short* __restrict__ W1, const unsigned short* __restrict__ W2,
    const float* __restrict__ b0, const float* __restrict__ b1, const float* __restrict__ b2,
    unsigned short* __restrict__ C0, unsigned short* __restrict__ C1,
    unsigned short* __restrict__ C2) {
  __shared__ unsigned short As[128 * 64];
  __shared__ unsigned short Bs[64 * 64];
  int z = blockIdx.z;
  if (z == 0) gemm_core64<1>(A0, W0, b0, C0, As, Bs);
  else if (z == 1) gemm_core64<1>(A1, W1, b1, C1, As, Bs);
  else gemm_core64<3>(A2, W2, b2, C2, As, Bs);
}

__global__ __launch_bounds__(256) void gemm_o(const unsigned short* __restrict__ A,
                                              const unsigned short* __restrict__ W,
                                              const float* __restrict__ bias,
                                              float* __restrict__ C) {
  __shared__ unsigned short As[128 * 64];
  __shared__ unsigned short Bs[64 * 64];
  gemm_core64<2>(A, W, bias, C, As, Bs);
}

// ---------------- fused cosine attention, 2x2 wave split + counted-vmcnt pass 2 ----------------
// R7 structure verbatim (validated 5x).
__global__ __launch_bounds__(256, 4) void attn_kernel(
    const unsigned short* __restrict__ Qn, const unsigned short* __restrict__ Kn,
    const unsigned short* __restrict__ Vt, const int* __restrict__ mask,
    const float* __restrict__ scale_p, float* __restrict__ attn_out,
    unsigned short* __restrict__ ctx) {
  __shared__ unsigned short QVs[64 * 128];  // Q [64q][128B] (8KB) then V [64d][256B] (16KB)
  __shared__ unsigned short Ks[128 * 64];   // [128k][128B] 16KB; f32 ctx scratch at end
  __shared__ unsigned short Ms[2048];       // mask as bf16 {0,1}, 4KB
  __shared__ float Rs[2][2][32];            // rowsum partials [qg][kg][q]

  // XCD-chunked swizzle: 1024 blocks, 128 per XCD -> 4 (b,h) K/V panels per XCD L2
  const int raw = blockIdx.x;
  const int swz = (raw & 7) * 128 + (raw >> 3);
  const int qt = swz & 31, h = (swz >> 5) & 15, b = swz >> 9;

  const int t = threadIdx.x, lane = t & 63, wid = t >> 6;
  const int lq = lane >> 4, lr = lane & 15;
  const int qg = wid >> 1, kg = wid & 1;
  const float k2 = scale_p[0] * 1.4426950408889634f;

  const unsigned short* Qg = Qn + ((size_t)(b * LSEQ + qt * 64) * DM + h * HD);
  const unsigned short* Kg = Kn + ((size_t)b * LSEQ * DM + h * HD);
  const unsigned short* Vg = Vt + (size_t)(b * NH + h) * HD * LSEQ;
  float* attn_g = attn_out + ((size_t)((b * NH + h) * LSEQ + qt * 64)) * LSEQ;
  const int* mg = mask + b * LSEQ;

  auto stageK = [&](int k0) {
#pragma unroll
    for (int i = 0; i < 4; ++i) {
      int chunk = i * 256 + t;
      int row = chunk >> 3, j = chunk & 7;
      async16(Kg + (size_t)(k0 + row) * DM + (j ^ (row & 7)) * 8, (char*)Ks + chunk * 16);
    }
  };
  auto stageV = [&](int k0) {
#pragma unroll
    for (int i = 0; i < 4; ++i) {
      int chunk = i * 256 + t;
      int row = chunk >> 4, j = chunk & 15;
      async16(Vg + (size_t)row * LSEQ + k0 + (j ^ (row & 15)) * 8, (char*)QVs + chunk * 16);
    }
  };

  // mask -> Ms (bf16 0/1)
  {
    const int4* mp = (const int4*)mg;
    int4 m0 = mp[t * 2], m1 = mp[t * 2 + 1];
    union { unsigned short u[8]; uint4 v; } mo;
    mo.u[0] = m0.x ? 0x3F80 : 0; mo.u[1] = m0.y ? 0x3F80 : 0;
    mo.u[2] = m0.z ? 0x3F80 : 0; mo.u[3] = m0.w ? 0x3F80 : 0;
    mo.u[4] = m1.x ? 0x3F80 : 0; mo.u[5] = m1.y ? 0x3F80 : 0;
    mo.u[6] = m1.z ? 0x3F80 : 0; mo.u[7] = m1.w ? 0x3F80 : 0;
    ((uint4*)Ms)[t] = mo.v;
  }
  // stage Q + K tile 0
#pragma unroll
  for (int i = 0; i < 2; ++i) {
    int chunk = i * 256 + t;
    int row = chunk >> 3, j = chunk & 7;
    async16(Qg + (size_t)row * DM + (j ^ (row & 7)) * 8, (char*)QVs + chunk * 16);
  }
  stageK(0);

  bf16x8 qb[2][2];  // [qf][dh]
  float rs[2] = {0.f, 0.f};

  // ---- pass 1: denominators ----
  for (int kt = 0; kt < LSEQ / 128; ++kt) {
    __syncthreads();
    if (kt == 0) {
#pragma unroll
      for (int qf = 0; qf < 2; ++qf)
#pragma unroll
        for (int dh = 0; dh < 2; ++dh)
          qb[qf][dh] = lds_frag_swz(QVs, qg * 32 + qf * 16 + lr, dh * 64 + lq * 16);
    }
#pragma unroll
    for (int kf = 0; kf < 4; ++kf) {
      int krow = kg * 64 + kf * 16 + lr;
      bf16x8 a0 = lds_frag_swz(Ks, krow, lq * 16);
      bf16x8 a1 = lds_frag_swz(Ks, krow, 64 + lq * 16);
      ushort4 m4 = *(const ushort4*)&Ms[kt * 128 + kg * 64 + kf * 16 + lq * 4];
#pragma unroll
      for (int qf = 0; qf < 2; ++qf) {
        f32x4 z = (f32x4){0.f, 0.f, 0.f, 0.f};
        z = __builtin_amdgcn_mfma_f32_16x16x32_bf16(a0, qb[qf][0], z, 0, 0, 0);
        z = __builtin_amdgcn_mfma_f32_16x16x32_bf16(a1, qb[qf][1], z, 0, 0, 0);
        rs[qf] += __builtin_amdgcn_exp2f(z[0] * k2) * bf16f(m4.x);
        rs[qf] += __builtin_amdgcn_exp2f(z[1] * k2) * bf16f(m4.y);
        rs[qf] += __builtin_amdgcn_exp2f(z[2] * k2) * bf16f(m4.z);
        rs[qf] += __builtin_amdgcn_exp2f(z[3] * k2) * bf16f(m4.w);
      }
    }
    __syncthreads();
    if (kt + 1 < LSEQ / 128) stageK((kt + 1) * 128);
  }
  // reduce rs over lq within wave, publish per (qg,kg); fold staging of tile 0
  // into the same barrier (all waves passed last B2, so Ks/QVs reads are done).
#pragma unroll
  for (int qf = 0; qf < 2; ++qf) {
    rs[qf] += __shfl_xor(rs[qf], 16, 64);
    rs[qf] += __shfl_xor(rs[qf], 32, 64);
  }
  stageK(0);
  stageV(0);
  if (lq == 0) {
    Rs[qg][kg][lr] = rs[0];
    Rs[qg][kg][16 + lr] = rs[1];
  }
  __syncthreads();  // drains vmcnt(0): tile-0 staging complete + Rs visible
  float sinv[2];
#pragma unroll
  for (int qf = 0; qf < 2; ++qf) {
    float tot = Rs[qg][0][qf * 16 + lr] + Rs[qg][1][qf * 16 + lr];
    sinv[qf] = 1.0f / fmaxf(tot, 1e-30f);
  }

  // ---- pass 2: recompute, accumulate PV, deferred NT attn stores ----
  f32x4 acc[4][2];  // [df][qf]
#pragma unroll
  for (int df = 0; df < 4; ++df)
#pragma unroll
    for (int qf = 0; qf < 2; ++qf) acc[df][qf] = (f32x4){0.f, 0.f, 0.f, 0.f};
  const int sA = ((lane & 16) ? 32 : 0) + lr;  // bpermute source lanes
  const int sB = sA + 16;
  const bool selHi = (lane & 32) != 0;

#pragma unroll 1
  for (int kt = 0; kt < LSEQ / 128; ++kt) {
    unsigned pk[4][2][2];
#pragma unroll
    for (int kf = 0; kf < 4; ++kf) {
      int krow = kg * 64 + kf * 16 + lr;
      bf16x8 a0 = lds_frag_swz(Ks, krow, lq * 16);
      bf16x8 a1 = lds_frag_swz(Ks, krow, 64 + lq * 16);
      ushort4 m4 = *(const ushort4*)&Ms[kt * 128 + kg * 64 + kf * 16 + lq * 4];
#pragma unroll
      for (int qf = 0; qf < 2; ++qf) {
        f32x4 z = (f32x4){0.f, 0.f, 0.f, 0.f};
        z = __builtin_amdgcn_mfma_f32_16x16x32_bf16(a0, qb[qf][0], z, 0, 0, 0);
        z = __builtin_amdgcn_mfma_f32_16x16x32_bf16(a1, qb[qf][1], z, 0, 0, 0);
        float p0 = __builtin_amdgcn_exp2f(z[0] * k2) * bf16f(m4.x) * sinv[qf];
        float p1 = __builtin_amdgcn_exp2f(z[1] * k2) * bf16f(m4.y) * sinv[qf];
        float p2 = __builtin_amdgcn_exp2f(z[2] * k2) * bf16f(m4.z) * sinv[qf];
        float p3 = __builtin_amdgcn_exp2f(z[3] * k2) * bf16f(m4.w) * sinv[qf];
        pk[kf][qf][0] = cvt_pk_bf16(p0, p1);
        pk[kf][qf][1] = cvt_pk_bf16(p2, p3);
      }
    }
    // PV: pb word j for lane lq covers keys kh*32+lq*8+2j{,+1}
#pragma unroll
    for (int kh = 0; kh < 2; ++kh) {
      bf16x8 pbv[2];
#pragma unroll
      for (int qf = 0; qf < 2; ++qf) {
        union { unsigned w[4]; bf16x8 v; } pb;
        unsigned lo0 = __shfl((int)pk[kh * 2][qf][0], sA, 64);
        unsigned hi0 = __shfl((int)pk[kh * 2 + 1][qf][0], sA, 64);
        unsigned lo1 = __shfl((int)pk[kh * 2][qf][1], sA, 64);
        unsigned hi1 = __shfl((int)pk[kh * 2 + 1][qf][1], sA, 64);
        unsigned lo2 = __shfl((int)pk[kh * 2][qf][0], sB, 64);
        unsigned hi2 = __shfl((int)pk[kh * 2 + 1][qf][0], sB, 64);
        unsigned lo3 = __shfl((int)pk[kh * 2][qf][1], sB, 64);
        unsigned hi3 = __shfl((int)pk[kh * 2 + 1][qf][1], sB, 64);
        pb.w[0] = selHi ? hi0 : lo0;
        pb.w[1] = selHi ? hi1 : lo1;
        pb.w[2] = selHi ? hi2 : lo2;
        pb.w[3] = selHi ? hi3 : lo3;
        pbv[qf] = pb.v;
      }
#pragma unroll
      for (int df = 0; df < 4; ++df) {
        bf16x8 va = lds_frag_swzV(QVs, df * 16 + lr, kg * 128 + kh * 64 + lq * 16);
#pragma unroll
        for (int qf = 0; qf < 2; ++qf)
          acc[df][qf] = __builtin_amdgcn_mfma_f32_16x16x32_bf16(va, pbv[qf], acc[df][qf], 0, 0, 0);
      }
    }
    // B2: all LDS reads of this tile done (lgkm only — do NOT drain NT stores)
    asm volatile("s_waitcnt lgkmcnt(0)" ::: "memory");
    __builtin_amdgcn_s_barrier();
    // stage next tile FIRST (8 older vmem loads)...
    if (kt + 1 < LSEQ / 128) { stageK((kt + 1) * 128); stageV((kt + 1) * 128); }
    __builtin_amdgcn_sched_barrier(0);
    // ...then this tile's 8 NT attn stores (youngest 8 vmem ops)
#pragma unroll
    for (int kf = 0; kf < 4; ++kf)
#pragma unroll
      for (int qf = 0; qf < 2; ++qf) {
        unsigned w0 = pk[kf][qf][0], w1 = pk[kf][qf][1];
        f32x4 st;
        st[0] = __builtin_bit_cast(float, w0 << 16);
        st[1] = __builtin_bit_cast(float, w0 & 0xFFFF0000u);
        st[2] = __builtin_bit_cast(float, w1 << 16);
        st[3] = __builtin_bit_cast(float, w1 & 0xFFFF0000u);
        __builtin_nontemporal_store(
            st, (f32x4*)(attn_g + (size_t)(qg * 32 + qf * 16 + lr) * LSEQ + kt * 128 +
                         kg * 64 + kf * 16 + lq * 4));
      }
    if (kt + 1 < LSEQ / 128) {
      // B1: staging retired (8 youngest = our stores may remain in flight)
      asm volatile("s_waitcnt vmcnt(8)" ::: "memory");
      __builtin_amdgcn_s_barrier();
    }
  }

  // ---- cross-wave k-reduction via LDS scratch (overlaid on Ks) ----
  __syncthreads();  // drains last tile's stores once (kernel epilogue)
  float* CR = (float*)Ks;  // [2 qg][32 q][64 d] f32, 16KB, swizzled
  if (kg == 1) {
#pragma unroll
    for (int df = 0; df < 4; ++df)
#pragma unroll
      for (int qf = 0; qf < 2; ++qf) {
        int q = qf * 16 + lr, dd = df * 16 + lq * 4;
        int byte = ((qg * 32 + q) * 64 + dd) * 4;
        byte ^= (q & 7) << 4;
        *(f32x4*)((char*)CR + byte) = acc[df][qf];
      }
  }
  __syncthreads();
  if (kg == 0) {
#pragma unroll
    for (int df = 0; df < 4; ++df)
#pragma unroll
      for (int qf = 0; qf < 2; ++qf) {
        int q = qf * 16 + lr, dd = df * 16 + lq * 4;
        int byte = ((qg * 32 + q) * 64 + dd) * 4;
        byte ^= (q & 7) << 4;
        f32x4 o = *(const f32x4*)((const char*)CR + byte);
        o += acc[df][qf];
        ushort4 st;
        st.x = bf16r(o[0]); st.y = bf16r(o[1]); st.z = bf16r(o[2]); st.w = bf16r(o[3]);
        *(ushort4*)&ctx[(size_t)(b * LSEQ + qt * 64 + qg * 32 + q) * DM + h * HD + dd] = st;
      }
  }
}

extern "C" void kernel_launch(void* const* d_in, const int* in_sizes, int n_in,
                              void* d_out, int out_size, void* d_ws, size_t ws_size,
                              hipStream_t stream) {
  const float* query = (const float*)d_in[0];
  const float* key_ = (const float*)d_in[1];
  const float* value = (const float*)d_in[2];
  const int* mask = (const int*)d_in[3];
  const float* Wq = (const float*)d_in[4];
  const float* bq = (const float*)d_in[5];
  const float* Wk = (const float*)d_in[6];
  const float* bk = (const float*)d_in[7];
  const float* Wv = (const float*)d_in[8];
  const float* bv = (const float*)d_in[9];
  const float* Wo = (const float*)d_in[10];
  const float* bo = (const float*)d_in[11];
  const float* scale = (const float*)d_in[12];

  char* ws = (char*)d_ws;
  const size_t XB = 8388608;   // 4Mi bf16
  const size_t WB = 2097152;   // 1Mi bf16
  unsigned short* qb = (unsigned short*)(ws);
  unsigned short* kb = (unsigned short*)(ws + XB);
  unsigned short* vb = (unsigned short*)(ws + 2 * XB);
  unsigned short* wqb = (unsigned short*)(ws + 3 * XB);
  unsigned short* wkb = (unsigned short*)(ws + 3 * XB + WB);
  unsigned short* wvb = (unsigned short*)(ws + 3 * XB + 2 * WB);
  unsigned short* wob = (unsigned short*)(ws + 3 * XB + 3 * WB);
  unsigned short* Qnb = (unsigned short*)(ws + 3 * XB + 4 * WB);
  unsigned short* Knb = (unsigned short*)(ws + 4 * XB + 4 * WB);
  unsigned short* Vtb = (unsigned short*)(ws + 5 * XB + 4 * WB);
  unsigned short* ctxb = (unsigned short*)(ws + 6 * XB + 4 * WB);

  cvt7<<<dim3(2048, 7), 256, 0, stream>>>(query, key_, value, Wq, Wk, Wv, Wo,
                                          qb, kb, vb, wqb, wkb, wvb, wob);

  gemm_qkv<<<dim3(32, 16, 3), 256, 0, stream>>>(qb, kb, vb, wqb, wkb, wvb, bq, bk, bv,
                                                Qnb, Knb, Vtb);

  float* attn_out = (float*)d_out + 4194304;
  attn_kernel<<<1024, 256, 0, stream>>>(Qnb, Knb, Vtb, mask, scale, attn_out, ctxb);

  gemm_o<<<dim3(32, 16), 256, 0, stream>>>(ctxb, wob, bo, (float*)d_out);
}